// Round 1
// baseline (232.591 us; speedup 1.0000x reference)
//
#include <hip/hip_runtime.h>

typedef __bf16 bf16x8 __attribute__((ext_vector_type(8)));
typedef float f32x4 __attribute__((ext_vector_type(4)));
typedef unsigned short u16;
typedef unsigned int u32;

// round-to-nearest-even f32 -> bf16
__device__ __forceinline__ u16 f2bf(float f) {
  u32 u = __builtin_bit_cast(u32, f);
  u += 0x7fffu + ((u >> 16) & 1u);
  return (u16)(u >> 16);
}

// async global->LDS, 16B per lane. LDS dest = wave-uniform base + lane*16.
__device__ __forceinline__ void gl_lds16(const u16* g, u16* l) {
  __builtin_amdgcn_global_load_lds(
      (const __attribute__((address_space(1))) u32*)g,
      (__attribute__((address_space(3))) u32*)l, 16, 0, 0);
}

// ---------------- cast x: f32 -> bf16, 8 elems/thread ----------------
__global__ __launch_bounds__(256) void k_cast(const float* __restrict__ in,
                                              u16* __restrict__ out, int n8) {
  int i = blockIdx.x * 256 + threadIdx.x;
  if (i >= n8) return;
  const float4* p = (const float4*)in + (size_t)i * 2;
  float4 a = p[0], b = p[1];
  u16 r[8] = {f2bf(a.x), f2bf(a.y), f2bf(a.z), f2bf(a.w),
              f2bf(b.x), f2bf(b.y), f2bf(b.z), f2bf(b.w)};
  ((uint4*)out)[i] = *(const uint4*)r;
}

// ---------- transpose+cast: W [K][N] f32 -> Wt [N][K] bf16 ----------
__global__ __launch_bounds__(256) void k_tcast(const float* __restrict__ in,
                                               u16* __restrict__ out, int K, int N) {
  __shared__ float tile[32][33];
  int n0 = blockIdx.x * 32, k0 = blockIdx.y * 32;
  int c = threadIdx.x & 31, r0 = (threadIdx.x >> 5) * 4;
#pragma unroll
  for (int rr = 0; rr < 4; ++rr) {
    int r = r0 + rr;
    tile[r][c] = in[(size_t)(k0 + r) * N + n0 + c];
  }
  __syncthreads();
#pragma unroll
  for (int rr = 0; rr < 4; ++rr) {
    int r = r0 + rr;
    out[(size_t)(n0 + r) * K + k0 + c] = f2bf(tile[c][r]);
  }
}

// ---------------- bf16 GEMM: C[M,N] = A[M,K] * Bt[N,K]^T ----------------
// 128x128 tile, 4 waves (2x2), BK=32. LDS chunk-swizzle: pchunk = chunk ^ ((row>>1)&3).
// EPI 0: split/scale into Q,K,V [B=2,H=16,T=2048,HD=64] bf16 (Q *= 0.125).
// EPI 1: write f32 C (row stride 1024).
template <int EPI>
__global__ __launch_bounds__(256) void k_gemm(const u16* __restrict__ A,
                                              const u16* __restrict__ Bt,
                                              u16* __restrict__ Qp, u16* __restrict__ Kp,
                                              u16* __restrict__ Vp, float* __restrict__ Cf,
                                              int K) {
  __shared__ u16 As[128 * 32];
  __shared__ u16 Bs[128 * 32];
  const int tid = threadIdx.x;
  const int lane = tid & 63, wave = tid >> 6;
  const int l15 = lane & 15, l4 = lane >> 4;
  const int wr = wave >> 1, wc = wave & 1;
  const int tm = blockIdx.y, tn = blockIdx.x;

  int srow[2], scol[2];
#pragma unroll
  for (int i = 0; i < 2; ++i) {
    int row = (wave * 2 + i) * 16 + (lane >> 2);
    srow[i] = row;
    scol[i] = ((lane & 3) ^ ((row >> 1) & 3)) * 8;  // pre-swizzled logical col
  }

  const f32x4 fz = {0.f, 0.f, 0.f, 0.f};
  f32x4 acc[4][4];
#pragma unroll
  for (int a = 0; a < 4; ++a)
#pragma unroll
    for (int b = 0; b < 4; ++b) acc[a][b] = fz;

  const int nk = K >> 5;
  for (int kt = 0; kt < nk; ++kt) {
#pragma unroll
    for (int i = 0; i < 2; ++i) {
      gl_lds16(A + (size_t)(tm * 128 + srow[i]) * K + kt * 32 + scol[i],
               &As[(wave * 2 + i) * 512]);
      gl_lds16(Bt + (size_t)(tn * 128 + srow[i]) * K + kt * 32 + scol[i],
               &Bs[(wave * 2 + i) * 512]);
    }
    __syncthreads();
    bf16x8 af[4], bfr[4];
#pragma unroll
    for (int mi = 0; mi < 4; ++mi) {
      int row = wr * 64 + mi * 16 + l15;
      int pch = l4 ^ ((row >> 1) & 3);
      af[mi] = *(const bf16x8*)&As[row * 32 + pch * 8];
    }
#pragma unroll
    for (int ni = 0; ni < 4; ++ni) {
      int row = wc * 64 + ni * 16 + l15;
      int pch = l4 ^ ((row >> 1) & 3);
      bfr[ni] = *(const bf16x8*)&Bs[row * 32 + pch * 8];
    }
#pragma unroll
    for (int mi = 0; mi < 4; ++mi)
#pragma unroll
      for (int ni = 0; ni < 4; ++ni)
        acc[mi][ni] = __builtin_amdgcn_mfma_f32_16x16x32_bf16(af[mi], bfr[ni],
                                                              acc[mi][ni], 0, 0, 0);
    __syncthreads();
  }

  const int rbase = tm * 128 + wr * 64 + l4 * 4;
  const int cbase = tn * 128 + wc * 64 + l15;
  if (EPI == 0) {
#pragma unroll
    for (int ni = 0; ni < 4; ++ni) {
      int col = cbase + ni * 16;
      int which = col >> 10;
      int d = col & 1023;
      int h = d >> 6, hd = d & 63;
      u16* dst = which == 0 ? Qp : (which == 1 ? Kp : Vp);
      float scl = which == 0 ? 0.125f : 1.0f;
#pragma unroll
      for (int mi = 0; mi < 4; ++mi) {
#pragma unroll
        for (int r = 0; r < 4; ++r) {
          int rowg = rbase + mi * 16 + r;
          int b = rowg >> 11, t = rowg & 2047;
          dst[(size_t)(((b * 16 + h) * 2048 + t) * 64 + hd)] = f2bf(acc[mi][ni][r] * scl);
        }
      }
    }
  } else {
#pragma unroll
    for (int mi = 0; mi < 4; ++mi)
#pragma unroll
      for (int r = 0; r < 4; ++r) {
        int rowg = rbase + mi * 16 + r;
#pragma unroll
        for (int ni = 0; ni < 4; ++ni)
          Cf[(size_t)rowg * 1024 + cbase + ni * 16] = acc[mi][ni][r];
      }
  }
}

// ---------------- causal flash attention ----------------
// grid (qt=32, bh=32), 4 waves; wave owns 16 q-rows. K/V tiles of 64.
// Q pre-scaled by 1/8 at GEMM1 epilogue. Y written as [B,T,H*HD] bf16.
__global__ __launch_bounds__(256) void k_attn(const u16* __restrict__ Q,
                                              const u16* __restrict__ K,
                                              const u16* __restrict__ V,
                                              u16* __restrict__ Y) {
  __shared__ u16 Kl[64 * 64];   // [kk][hd], chunk ^= kk&7
  __shared__ u16 Vt[64 * 64];   // [hd][k],  chunk ^= (hd&7)^((hd>>3)&7)
  __shared__ u16 Pl[4 * 16 * 64];  // per-wave [q][k], chunk ^= q&7
  const int tid = threadIdx.x, lane = tid & 63, wave = tid >> 6;
  const int l15 = lane & 15, l4 = lane >> 4;
  const int qt = blockIdx.x, bh = blockIdx.y;
  const u16* Qb = Q + (size_t)bh * 2048 * 64;
  const u16* Kb = K + (size_t)bh * 2048 * 64;
  const u16* Vb = V + (size_t)bh * 2048 * 64;

  bf16x8 qf[2];
  {
    int qrow = qt * 64 + wave * 16 + l15;
#pragma unroll
    for (int s = 0; s < 2; ++s)
      qf[s] = *(const bf16x8*)&Qb[(size_t)qrow * 64 + s * 32 + l4 * 8];
  }

  const f32x4 fz = {0.f, 0.f, 0.f, 0.f};
  f32x4 accO[4];
  float m[4], lsum[4];
#pragma unroll
  for (int i = 0; i < 4; ++i) {
    accO[i] = fz;
    m[i] = -1e30f;
    lsum[i] = 0.f;
  }

  for (int kt = 0; kt <= qt; ++kt) {
    // stage K: linear LDS dest, pre-swizzled global source
#pragma unroll
    for (int i = 0; i < 2; ++i) {
      int kk = (wave * 2 + i) * 8 + (lane >> 3);
      int lcol = ((lane & 7) ^ (kk & 7)) * 8;
      gl_lds16(Kb + (size_t)(kt * 64 + kk) * 64 + lcol, &Kl[(wave * 2 + i) * 512]);
    }
    // stage V^T, swizzled scalar writes
#pragma unroll
    for (int i = 0; i < 2; ++i) {
      int g = i * 256 + tid;
      int tt = g >> 3, hd0 = (g & 7) * 8;
      uint4 raw = *(const uint4*)&Vb[(size_t)(kt * 64 + tt) * 64 + hd0];
      const u16* pv = (const u16*)&raw;
#pragma unroll
      for (int j = 0; j < 8; ++j) {
        int hd = hd0 + j;
        int f = (hd & 7) ^ ((hd >> 3) & 7);
        Vt[hd * 64 + (((tt >> 3) ^ f) * 8) + (tt & 7)] = pv[j];
      }
    }
    __syncthreads();

    // S = Q K^T : accS[nb] rows q=l4*4+r, cols k=nb*16+l15
    f32x4 accS[4] = {fz, fz, fz, fz};
#pragma unroll
    for (int s = 0; s < 2; ++s) {
#pragma unroll
      for (int nb = 0; nb < 4; ++nb) {
        int kk = nb * 16 + l15;
        int ch = (s * 4 + l4) ^ (kk & 7);
        bf16x8 kf = *(const bf16x8*)&Kl[kk * 64 + ch * 8];
        accS[nb] = __builtin_amdgcn_mfma_f32_16x16x32_bf16(qf[s], kf, accS[nb], 0, 0, 0);
      }
    }

    // causal mask (diagonal tile only) + online softmax
    float sv[4][4];
    const bool diag = (kt == qt);
#pragma unroll
    for (int nb = 0; nb < 4; ++nb)
#pragma unroll
      for (int r = 0; r < 4; ++r) {
        float s = accS[nb][r];
        if (diag) {
          int kg = nb * 16 + l15;
          int qg = wave * 16 + l4 * 4 + r;
          if (kg > qg) s = -1e30f;
        }
        sv[nb][r] = s;
      }
    float mnew[4], alpha[4];
#pragma unroll
    for (int r = 0; r < 4; ++r) {
      float mx = fmaxf(fmaxf(sv[0][r], sv[1][r]), fmaxf(sv[2][r], sv[3][r]));
#pragma unroll
      for (int d = 1; d < 16; d <<= 1) mx = fmaxf(mx, __shfl_xor(mx, d));
      mnew[r] = fmaxf(m[r], mx);
      alpha[r] = __expf(m[r] - mnew[r]);
      m[r] = mnew[r];
    }
    float rsum[4] = {0.f, 0.f, 0.f, 0.f};
#pragma unroll
    for (int nb = 0; nb < 4; ++nb)
#pragma unroll
      for (int r = 0; r < 4; ++r) {
        float p = __expf(sv[nb][r] - mnew[r]);
        rsum[r] += p;
        int q = l4 * 4 + r, k = nb * 16 + l15;
        Pl[wave * 1024 + q * 64 + (((k >> 3) ^ (q & 7)) * 8) + (k & 7)] = f2bf(p);
      }
#pragma unroll
    for (int r = 0; r < 4; ++r) {
      float s = rsum[r];
#pragma unroll
      for (int d = 1; d < 16; d <<= 1) s += __shfl_xor(s, d);
      lsum[r] = lsum[r] * alpha[r] + s;
    }
#pragma unroll
    for (int hb = 0; hb < 4; ++hb)
#pragma unroll
      for (int r = 0; r < 4; ++r) accO[hb][r] *= alpha[r];

    // O += P V
#pragma unroll
    for (int s = 0; s < 2; ++s) {
      int q = l15;
      int ch = (s * 4 + l4) ^ (q & 7);
      bf16x8 pf = *(const bf16x8*)&Pl[wave * 1024 + q * 64 + ch * 8];
#pragma unroll
      for (int hb = 0; hb < 4; ++hb) {
        int hd = hb * 16 + l15;
        int f = (hd & 7) ^ ((hd >> 3) & 7);
        int ch2 = (s * 4 + l4) ^ f;
        bf16x8 vf = *(const bf16x8*)&Vt[hd * 64 + ch2 * 8];
        accO[hb] = __builtin_amdgcn_mfma_f32_16x16x32_bf16(pf, vf, accO[hb], 0, 0, 0);
      }
    }
    __syncthreads();
  }

  const int b = bh >> 4, h = bh & 15;
#pragma unroll
  for (int r = 0; r < 4; ++r) {
    int qg = qt * 64 + wave * 16 + l4 * 4 + r;
    float inv = 1.0f / lsum[r];
#pragma unroll
    for (int hb = 0; hb < 4; ++hb) {
      int hd = hb * 16 + l15;
      Y[(size_t)(b * 2048 + qg) * 1024 + h * 64 + hd] = f2bf(accO[hb][r] * inv);
    }
  }
}

extern "C" void kernel_launch(void* const* d_in, const int* in_sizes, int n_in,
                              void* d_out, int out_size, void* d_ws, size_t ws_size,
                              hipStream_t stream) {
  const float* x = (const float*)d_in[0];       // [2,2048,1024]
  const float* Wqkv = (const float*)d_in[1];    // [1024,3072]
  const float* Wproj = (const float*)d_in[2];   // [1024,1024]
  float* out = (float*)d_out;                   // [2,2048,1024] f32

  char* ws = (char*)d_ws;
  u16* Xb  = (u16*)(ws + 0);                    // 8 MB  [4096][1024]
  u16* Wqt = (u16*)(ws + ((size_t)8 << 20));    // 6 MB  [3072][1024]
  u16* Wpt = (u16*)(ws + ((size_t)14 << 20));   // 2 MB  [1024][1024]
  u16* Qs  = (u16*)(ws + ((size_t)16 << 20));   // 8 MB  [2,16,2048,64]
  u16* Ks  = (u16*)(ws + ((size_t)24 << 20));   // 8 MB
  u16* Vs  = (u16*)(ws + ((size_t)32 << 20));   // 8 MB
  u16* Yb  = (u16*)(ws + ((size_t)40 << 20));   // 8 MB  [4096][1024]

  k_cast<<<2048, 256, 0, stream>>>(x, Xb, 4096 * 1024 / 8);
  k_tcast<<<dim3(96, 32), 256, 0, stream>>>(Wqkv, Wqt, 1024, 3072);
  k_tcast<<<dim3(32, 32), 256, 0, stream>>>(Wproj, Wpt, 1024, 1024);
  k_gemm<0><<<dim3(24, 32), 256, 0, stream>>>(Xb, Wqt, Qs, Ks, Vs, nullptr, 1024);
  k_attn<<<dim3(32, 32), 256, 0, stream>>>(Qs, Ks, Vs, Yb);
  k_gemm<1><<<dim3(8, 32), 256, 0, stream>>>(Yb, Wpt, nullptr, nullptr, nullptr, out, 1024);
}

// Round 2
// 133.652 us; speedup vs baseline: 1.7403x; 1.7403x over previous
//
#include <hip/hip_runtime.h>

typedef __bf16 bf16x8 __attribute__((ext_vector_type(8)));
typedef float f32x4 __attribute__((ext_vector_type(4)));
typedef unsigned short u16;
typedef unsigned int u32;

// round-to-nearest-even f32 -> bf16
__device__ __forceinline__ u16 f2bf(float f) {
  u32 u = __builtin_bit_cast(u32, f);
  u += 0x7fffu + ((u >> 16) & 1u);
  return (u16)(u >> 16);
}

// packed f32x2 -> bf16x2 (RNE), single instruction
__device__ __forceinline__ u32 cvt_pk_bf16(float lo, float hi) {
  u32 r;
  asm("v_cvt_pk_bf16_f32 %0, %1, %2" : "=v"(r) : "v"(lo), "v"(hi));
  return r;
}

// async global->LDS, 16B per lane. LDS dest = wave-uniform base + lane*16.
__device__ __forceinline__ void gl_lds16(const u16* g, u16* l) {
  __builtin_amdgcn_global_load_lds(
      (const __attribute__((address_space(1))) u32*)g,
      (__attribute__((address_space(3))) u32*)l, 16, 0, 0);
}

// ---------------- cast x: f32 -> bf16, 8 elems/thread ----------------
__global__ __launch_bounds__(256) void k_cast(const float* __restrict__ in,
                                              u16* __restrict__ out, int n8) {
  int i = blockIdx.x * 256 + threadIdx.x;
  if (i >= n8) return;
  const float4* p = (const float4*)in + (size_t)i * 2;
  float4 a = p[0], b = p[1];
  u16 r[8] = {f2bf(a.x), f2bf(a.y), f2bf(a.z), f2bf(a.w),
              f2bf(b.x), f2bf(b.y), f2bf(b.z), f2bf(b.w)};
  ((uint4*)out)[i] = *(const uint4*)r;
}

// ---------- transpose+cast: W [K][N] f32 -> Wt [N][K] bf16 ----------
__global__ __launch_bounds__(256) void k_tcast(const float* __restrict__ in,
                                               u16* __restrict__ out, int K, int N) {
  __shared__ float tile[32][33];
  int n0 = blockIdx.x * 32, k0 = blockIdx.y * 32;
  int c = threadIdx.x & 31, r0 = (threadIdx.x >> 5) * 4;
#pragma unroll
  for (int rr = 0; rr < 4; ++rr) {
    int r = r0 + rr;
    tile[r][c] = in[(size_t)(k0 + r) * N + n0 + c];
  }
  __syncthreads();
#pragma unroll
  for (int rr = 0; rr < 4; ++rr) {
    int r = r0 + rr;
    out[(size_t)(n0 + r) * K + k0 + c] = f2bf(tile[c][r]);
  }
}

// ---------------- bf16 GEMM: C[M,N] = A[M,K] * Bt[N,K]^T ----------------
// 128x128 tile, 4 waves (2x2), BK=32. LDS chunk-swizzle: pchunk = chunk ^ ((row>>1)&3).
template <int EPI>
__global__ __launch_bounds__(256) void k_gemm(const u16* __restrict__ A,
                                              const u16* __restrict__ Bt,
                                              u16* __restrict__ Qp, u16* __restrict__ Kp,
                                              u16* __restrict__ Vp, float* __restrict__ Cf,
                                              int K) {
  __shared__ u16 As[128 * 32];
  __shared__ u16 Bs[128 * 32];
  const int tid = threadIdx.x;
  const int lane = tid & 63, wave = tid >> 6;
  const int l15 = lane & 15, l4 = lane >> 4;
  const int wr = wave >> 1, wc = wave & 1;
  const int tm = blockIdx.y, tn = blockIdx.x;

  int srow[2], scol[2];
#pragma unroll
  for (int i = 0; i < 2; ++i) {
    int row = (wave * 2 + i) * 16 + (lane >> 2);
    srow[i] = row;
    scol[i] = ((lane & 3) ^ ((row >> 1) & 3)) * 8;
  }

  const f32x4 fz = {0.f, 0.f, 0.f, 0.f};
  f32x4 acc[4][4];
#pragma unroll
  for (int a = 0; a < 4; ++a)
#pragma unroll
    for (int b = 0; b < 4; ++b) acc[a][b] = fz;

  const int nk = K >> 5;
  for (int kt = 0; kt < nk; ++kt) {
#pragma unroll
    for (int i = 0; i < 2; ++i) {
      gl_lds16(A + (size_t)(tm * 128 + srow[i]) * K + kt * 32 + scol[i],
               &As[(wave * 2 + i) * 512]);
      gl_lds16(Bt + (size_t)(tn * 128 + srow[i]) * K + kt * 32 + scol[i],
               &Bs[(wave * 2 + i) * 512]);
    }
    __syncthreads();
    bf16x8 af[4], bfr[4];
#pragma unroll
    for (int mi = 0; mi < 4; ++mi) {
      int row = wr * 64 + mi * 16 + l15;
      int pch = l4 ^ ((row >> 1) & 3);
      af[mi] = *(const bf16x8*)&As[row * 32 + pch * 8];
    }
#pragma unroll
    for (int ni = 0; ni < 4; ++ni) {
      int row = wc * 64 + ni * 16 + l15;
      int pch = l4 ^ ((row >> 1) & 3);
      bfr[ni] = *(const bf16x8*)&Bs[row * 32 + pch * 8];
    }
#pragma unroll
    for (int mi = 0; mi < 4; ++mi)
#pragma unroll
      for (int ni = 0; ni < 4; ++ni)
        acc[mi][ni] = __builtin_amdgcn_mfma_f32_16x16x32_bf16(af[mi], bfr[ni],
                                                              acc[mi][ni], 0, 0, 0);
    __syncthreads();
  }

  const int rbase = tm * 128 + wr * 64 + l4 * 4;
  const int cbase = tn * 128 + wc * 64 + l15;
  if (EPI == 0) {
#pragma unroll
    for (int ni = 0; ni < 4; ++ni) {
      int col = cbase + ni * 16;
      int which = col >> 10;
      int d = col & 1023;
      int h = d >> 6, hd = d & 63;
      u16* dst = which == 0 ? Qp : (which == 1 ? Kp : Vp);
      float scl = which == 0 ? 0.125f : 1.0f;
#pragma unroll
      for (int mi = 0; mi < 4; ++mi) {
#pragma unroll
        for (int r = 0; r < 4; ++r) {
          int rowg = rbase + mi * 16 + r;
          int b = rowg >> 11, t = rowg & 2047;
          dst[(size_t)(((b * 16 + h) * 2048 + t) * 64 + hd)] = f2bf(acc[mi][ni][r] * scl);
        }
      }
    }
  } else {
#pragma unroll
    for (int mi = 0; mi < 4; ++mi)
#pragma unroll
      for (int r = 0; r < 4; ++r) {
        int rowg = rbase + mi * 16 + r;
#pragma unroll
        for (int ni = 0; ni < 4; ++ni)
          Cf[(size_t)rowg * 1024 + cbase + ni * 16] = acc[mi][ni][r];
      }
  }
}

// ---------------- causal flash attention (v2) ----------------
// grid (pair=16, bh=32). Block processes q-tiles {31-p, p} sequentially -> 33 k-tiles
// per block, perfectly balanced. Double-buffered K/V^T LDS, one barrier per k-tile.
// Swapped QK^T: accS[nb] holds S[q=l15][k=nb*16+l4*4+r] -> per-lane scalar softmax.
__global__ __launch_bounds__(256) void k_attn(const u16* __restrict__ Q,
                                              const u16* __restrict__ K,
                                              const u16* __restrict__ V,
                                              u16* __restrict__ Y) {
  __shared__ u16 Kl[2][64 * 64];   // [kk][hd], chunk ^= kk&7
  __shared__ u16 Vt[2][64 * 64];   // [hd][k],  chunk ^= (hd&7)^((hd>>3)&7)
  __shared__ u16 Pl[4 * 16 * 64];  // per-wave [q][k], chunk ^= q&7
  const int tid = threadIdx.x, lane = tid & 63, wave = tid >> 6;
  const int l15 = lane & 15, l4 = lane >> 4;
  const int pr = blockIdx.x, bh = blockIdx.y;
  const u16* Qb = Q + (size_t)bh * 2048 * 64;
  const u16* Kb = K + (size_t)bh * 2048 * 64;
  const u16* Vb = V + (size_t)bh * 2048 * 64;
  const int b = bh >> 4, h = bh & 15;
  const f32x4 fz = {0.f, 0.f, 0.f, 0.f};

  // staging index precompute
  const int kk0 = wave * 16 + (lane >> 3);
  const int kk1 = kk0 + 8;
  const int lcol0 = ((lane & 7) ^ (kk0 & 7)) * 8;
  const int lcol1 = ((lane & 7) ^ (kk1 & 7)) * 8;
  const int vtt0 = tid >> 3, vtt1 = 32 + (tid >> 3), vhd0 = (tid & 7) * 8;
  const int pbase = wave * 1024 + l15 * 64;

  auto stageK = [&](int buf, int kt) {
    gl_lds16(Kb + (size_t)(kt * 64 + kk0) * 64 + lcol0, &Kl[buf][(wave * 2 + 0) * 512]);
    gl_lds16(Kb + (size_t)(kt * 64 + kk1) * 64 + lcol1, &Kl[buf][(wave * 2 + 1) * 512]);
  };
  auto vstore = [&](int buf, uint4 ra, uint4 rb) {
    const u16* pv = (const u16*)&ra;
#pragma unroll
    for (int j = 0; j < 8; ++j) {
      int hd = vhd0 + j;
      int f = (hd & 7) ^ ((hd >> 3) & 7);
      Vt[buf][hd * 64 + (((vtt0 >> 3) ^ f) * 8) + (vtt0 & 7)] = pv[j];
    }
    pv = (const u16*)&rb;
#pragma unroll
    for (int j = 0; j < 8; ++j) {
      int hd = vhd0 + j;
      int f = (hd & 7) ^ ((hd >> 3) & 7);
      Vt[buf][hd * 64 + (((vtt1 >> 3) ^ f) * 8) + (vtt1 & 7)] = pv[j];
    }
  };

#pragma unroll 1
  for (int half = 0; half < 2; ++half) {
    const int qt = half == 0 ? (31 - pr) : pr;
    bf16x8 qf[2];
    {
      int qrow = qt * 64 + wave * 16 + l15;
      qf[0] = *(const bf16x8*)&Qb[(size_t)qrow * 64 + l4 * 8];
      qf[1] = *(const bf16x8*)&Qb[(size_t)qrow * 64 + 32 + l4 * 8];
    }
    f32x4 accO[4] = {fz, fz, fz, fz};
    float m = -1e30f, lsum = 0.f;

    // prologue: stage tile 0 into buf 0
    stageK(0, 0);
    {
      uint4 ra = *(const uint4*)&Vb[(size_t)vtt0 * 64 + vhd0];
      uint4 rb = *(const uint4*)&Vb[(size_t)vtt1 * 64 + vhd0];
      vstore(0, ra, rb);
    }
    __syncthreads();

    int cur = 0;
#pragma unroll 1
    for (int kt = 0; kt <= qt; ++kt) {
      const int nxt = cur ^ 1;
      const bool pre = kt < qt;
      uint4 va, vb2;
      if (pre) {
        stageK(nxt, kt + 1);
        va = *(const uint4*)&Vb[(size_t)((kt + 1) * 64 + vtt0) * 64 + vhd0];
        vb2 = *(const uint4*)&Vb[(size_t)((kt + 1) * 64 + vtt1) * 64 + vhd0];
      }
      // QK^T swapped: mfma(K, Q)
      f32x4 accS[4] = {fz, fz, fz, fz};
#pragma unroll
      for (int s = 0; s < 2; ++s)
#pragma unroll
        for (int nb = 0; nb < 4; ++nb) {
          int kk = nb * 16 + l15;
          int ch = (s * 4 + l4) ^ (kk & 7);
          bf16x8 kf = *(const bf16x8*)&Kl[cur][kk * 64 + ch * 8];
          accS[nb] = __builtin_amdgcn_mfma_f32_16x16x32_bf16(kf, qf[s], accS[nb], 0, 0, 0);
        }
      // causal mask (diagonal tile only)
      float sv[4][4];
      if (kt == qt) {
        int qg = wave * 16 + l15;
#pragma unroll
        for (int nb = 0; nb < 4; ++nb)
#pragma unroll
          for (int r = 0; r < 4; ++r) {
            int kg = nb * 16 + l4 * 4 + r;
            sv[nb][r] = kg > qg ? -1e30f : accS[nb][r];
          }
      } else {
#pragma unroll
        for (int nb = 0; nb < 4; ++nb)
#pragma unroll
          for (int r = 0; r < 4; ++r) sv[nb][r] = accS[nb][r];
      }
      // per-lane online softmax (lane owns q = l15)
      float mx = sv[0][0];
#pragma unroll
      for (int nb = 0; nb < 4; ++nb)
#pragma unroll
        for (int r = 0; r < 4; ++r) mx = fmaxf(mx, sv[nb][r]);
      mx = fmaxf(mx, __shfl_xor(mx, 16));
      mx = fmaxf(mx, __shfl_xor(mx, 32));
      float mnew = fmaxf(m, mx);
      float alpha = __expf(m - mnew);
      m = mnew;
      float p[4][4];
      float rsum = 0.f;
#pragma unroll
      for (int nb = 0; nb < 4; ++nb)
#pragma unroll
        for (int r = 0; r < 4; ++r) {
          p[nb][r] = __expf(sv[nb][r] - mnew);
          rsum += p[nb][r];
        }
      rsum += __shfl_xor(rsum, 16);
      rsum += __shfl_xor(rsum, 32);
      lsum = lsum * alpha + rsum;
      // P -> LDS (8 dword stores, chunk-swizzled by q&7)
#pragma unroll
      for (int nb = 0; nb < 4; ++nb) {
        int c = nb * 2 + (l4 >> 1);
        int off = ((c ^ (l15 & 7)) * 8) + (l4 & 1) * 4;
        *(u32*)&Pl[pbase + off] = cvt_pk_bf16(p[nb][0], p[nb][1]);
        *(u32*)&Pl[pbase + off + 2] = cvt_pk_bf16(p[nb][2], p[nb][3]);
      }
      // rescale accO (O rows are q = l4*4+r -> fetch alpha from lane l4*4+r)
      float aO[4];
#pragma unroll
      for (int r = 0; r < 4; ++r) aO[r] = __shfl(alpha, l4 * 4 + r);
#pragma unroll
      for (int hb = 0; hb < 4; ++hb)
#pragma unroll
        for (int r = 0; r < 4; ++r) accO[hb][r] *= aO[r];
      // late V^T write for next tile (hides HBM latency under QK/softmax)
      if (pre) vstore(nxt, va, vb2);
      // O += P V
#pragma unroll
      for (int s = 0; s < 2; ++s) {
        int ch = (s * 4 + l4) ^ (l15 & 7);
        bf16x8 pf = *(const bf16x8*)&Pl[pbase + ch * 8];
#pragma unroll
        for (int hb = 0; hb < 4; ++hb) {
          int hd = hb * 16 + l15;
          int f = (hd & 7) ^ ((hd >> 3) & 7);
          int ch2 = (s * 4 + l4) ^ f;
          bf16x8 vf = *(const bf16x8*)&Vt[cur][hd * 64 + ch2 * 8];
          accO[hb] = __builtin_amdgcn_mfma_f32_16x16x32_bf16(pf, vf, accO[hb], 0, 0, 0);
        }
      }
      __syncthreads();
      cur = nxt;
    }
    // epilogue
#pragma unroll
    for (int r = 0; r < 4; ++r) {
      float ls = __shfl(lsum, l4 * 4 + r);
      float inv = 1.0f / ls;
      int qg = qt * 64 + wave * 16 + l4 * 4 + r;
#pragma unroll
      for (int hb = 0; hb < 4; ++hb)
        Y[(size_t)(b * 2048 + qg) * 1024 + h * 64 + hb * 16 + l15] =
            f2bf(accO[hb][r] * inv);
    }
  }
}

extern "C" void kernel_launch(void* const* d_in, const int* in_sizes, int n_in,
                              void* d_out, int out_size, void* d_ws, size_t ws_size,
                              hipStream_t stream) {
  const float* x = (const float*)d_in[0];       // [2,2048,1024]
  const float* Wqkv = (const float*)d_in[1];    // [1024,3072]
  const float* Wproj = (const float*)d_in[2];   // [1024,1024]
  float* out = (float*)d_out;                   // [2,2048,1024] f32

  char* ws = (char*)d_ws;
  u16* Xb  = (u16*)(ws + 0);                    // 8 MB  [4096][1024]
  u16* Wqt = (u16*)(ws + ((size_t)8 << 20));    // 6 MB  [3072][1024]
  u16* Wpt = (u16*)(ws + ((size_t)14 << 20));   // 2 MB  [1024][1024]
  u16* Qs  = (u16*)(ws + ((size_t)16 << 20));   // 8 MB  [2,16,2048,64]
  u16* Ks  = (u16*)(ws + ((size_t)24 << 20));   // 8 MB
  u16* Vs  = (u16*)(ws + ((size_t)32 << 20));   // 8 MB
  u16* Yb  = (u16*)(ws + ((size_t)40 << 20));   // 8 MB  [4096][1024]

  k_cast<<<2048, 256, 0, stream>>>(x, Xb, 4096 * 1024 / 8);
  k_tcast<<<dim3(96, 32), 256, 0, stream>>>(Wqkv, Wqt, 1024, 3072);
  k_tcast<<<dim3(32, 32), 256, 0, stream>>>(Wproj, Wpt, 1024, 1024);
  k_gemm<0><<<dim3(24, 32), 256, 0, stream>>>(Xb, Wqt, Qs, Ks, Vs, nullptr, 1024);
  k_attn<<<dim3(16, 32), 256, 0, stream>>>(Qs, Ks, Vs, Yb);
  k_gemm<1><<<dim3(8, 32), 256, 0, stream>>>(Yb, Wpt, nullptr, nullptr, nullptr, out, 1024);
}

// Round 4
// 128.848 us; speedup vs baseline: 1.8051x; 1.0373x over previous
//
#include <hip/hip_runtime.h>

typedef __bf16 bf16x8 __attribute__((ext_vector_type(8)));
typedef __bf16 bf16x4 __attribute__((ext_vector_type(4)));
typedef float f32x4 __attribute__((ext_vector_type(4)));
typedef unsigned short u16;
typedef unsigned int u32;
typedef u32 u32x4 __attribute__((ext_vector_type(4)));

// round-to-nearest-even f32 -> bf16
__device__ __forceinline__ u16 f2bf(float f) {
  u32 u = __builtin_bit_cast(u32, f);
  u += 0x7fffu + ((u >> 16) & 1u);
  return (u16)(u >> 16);
}

// packed f32x2 -> bf16x2 (RNE); low u16 = first arg (verified by R2 pass)
__device__ __forceinline__ u32 cvt_pk_bf16(float lo, float hi) {
  u32 r;
  asm("v_cvt_pk_bf16_f32 %0, %1, %2" : "=v"(r) : "v"(lo), "v"(hi));
  return r;
}

// async global->LDS, 16B per lane. LDS dest = wave-uniform base + lane*16.
__device__ __forceinline__ void gl_lds16(const u16* g, u16* l) {
  __builtin_amdgcn_global_load_lds(
      (const __attribute__((address_space(1))) u32*)g,
      (__attribute__((address_space(3))) u32*)l, 16, 0, 0);
}

// LDS transpose read. Per-lane address REQUIRED: pass p = base + lane*4 (elems).
// Lane l then receives elems base[(l>>4)*64 + j*16 + (l&15)], j=0..3
// (HW transposes each 16-lane group's 4x16 row-major subtile; uniform addr
//  would make all lanes read the same value -- the R3 bug).
__device__ __forceinline__ bf16x4 tr16(const u16* p) {
  bf16x4 r;
  auto lp = (const __attribute__((address_space(3))) u16*)p;
  asm volatile("ds_read_b64_tr_b16 %0, %1" : "=&v"(r) : "v"(lp));
  return r;
}

// ---------------- cast x: f32 -> bf16, 8 elems/thread ----------------
__global__ __launch_bounds__(256) void k_cast(const float* __restrict__ in,
                                              u16* __restrict__ out, int n8) {
  int i = blockIdx.x * 256 + threadIdx.x;
  if (i >= n8) return;
  const float4* p = (const float4*)in + (size_t)i * 2;
  float4 a = p[0], b = p[1];
  u16 r[8] = {f2bf(a.x), f2bf(a.y), f2bf(a.z), f2bf(a.w),
              f2bf(b.x), f2bf(b.y), f2bf(b.z), f2bf(b.w)};
  ((uint4*)out)[i] = *(const uint4*)r;
}

// ---------- transpose+cast: W [K][N] f32 -> Wt [N][K] bf16 ----------
__global__ __launch_bounds__(256) void k_tcast(const float* __restrict__ in,
                                               u16* __restrict__ out, int K, int N) {
  __shared__ float tile[32][33];
  int n0 = blockIdx.x * 32, k0 = blockIdx.y * 32;
  int c = threadIdx.x & 31, r0 = (threadIdx.x >> 5) * 4;
#pragma unroll
  for (int rr = 0; rr < 4; ++rr) {
    int r = r0 + rr;
    tile[r][c] = in[(size_t)(k0 + r) * N + n0 + c];
  }
  __syncthreads();
#pragma unroll
  for (int rr = 0; rr < 4; ++rr) {
    int r = r0 + rr;
    out[(size_t)(n0 + r) * K + k0 + c] = f2bf(tile[c][r]);
  }
}

// ---------------- bf16 GEMM: C[M,N] = A[M,K] * Bt[N,K]^T ----------------
// 128x128 tile, 4 waves (2x2), BK=32. LDS chunk-swizzle: pchunk = chunk ^ ((row>>1)&3).
template <int EPI>
__global__ __launch_bounds__(256) void k_gemm(const u16* __restrict__ A,
                                              const u16* __restrict__ Bt,
                                              u16* __restrict__ Qp, u16* __restrict__ Kp,
                                              u16* __restrict__ Vp, float* __restrict__ Cf,
                                              int K) {
  __shared__ u16 As[128 * 32];
  __shared__ u16 Bs[128 * 32];
  const int tid = threadIdx.x;
  const int lane = tid & 63, wave = tid >> 6;
  const int l15 = lane & 15, l4 = lane >> 4;
  const int wr = wave >> 1, wc = wave & 1;
  const int tm = blockIdx.y, tn = blockIdx.x;

  int srow[2], scol[2];
#pragma unroll
  for (int i = 0; i < 2; ++i) {
    int row = (wave * 2 + i) * 16 + (lane >> 2);
    srow[i] = row;
    scol[i] = ((lane & 3) ^ ((row >> 1) & 3)) * 8;
  }

  const f32x4 fz = {0.f, 0.f, 0.f, 0.f};
  f32x4 acc[4][4];
#pragma unroll
  for (int a = 0; a < 4; ++a)
#pragma unroll
    for (int b = 0; b < 4; ++b) acc[a][b] = fz;

  const int nk = K >> 5;
  for (int kt = 0; kt < nk; ++kt) {
#pragma unroll
    for (int i = 0; i < 2; ++i) {
      gl_lds16(A + (size_t)(tm * 128 + srow[i]) * K + kt * 32 + scol[i],
               &As[(wave * 2 + i) * 512]);
      gl_lds16(Bt + (size_t)(tn * 128 + srow[i]) * K + kt * 32 + scol[i],
               &Bs[(wave * 2 + i) * 512]);
    }
    __syncthreads();
    bf16x8 af[4], bfr[4];
#pragma unroll
    for (int mi = 0; mi < 4; ++mi) {
      int row = wr * 64 + mi * 16 + l15;
      int pch = l4 ^ ((row >> 1) & 3);
      af[mi] = *(const bf16x8*)&As[row * 32 + pch * 8];
    }
#pragma unroll
    for (int ni = 0; ni < 4; ++ni) {
      int row = wc * 64 + ni * 16 + l15;
      int pch = l4 ^ ((row >> 1) & 3);
      bfr[ni] = *(const bf16x8*)&Bs[row * 32 + pch * 8];
    }
#pragma unroll
    for (int mi = 0; mi < 4; ++mi)
#pragma unroll
      for (int ni = 0; ni < 4; ++ni)
        acc[mi][ni] = __builtin_amdgcn_mfma_f32_16x16x32_bf16(af[mi], bfr[ni],
                                                              acc[mi][ni], 0, 0, 0);
    __syncthreads();
  }

  const int rbase = tm * 128 + wr * 64 + l4 * 4;
  const int cbase = tn * 128 + wc * 64 + l15;
  if (EPI == 0) {
#pragma unroll
    for (int ni = 0; ni < 4; ++ni) {
      int col = cbase + ni * 16;
      int which = col >> 10;
      int d = col & 1023;
      int h = d >> 6, hd = d & 63;
      u16* dst = which == 0 ? Qp : (which == 1 ? Kp : Vp);
      float scl = which == 0 ? 0.125f : 1.0f;
#pragma unroll
      for (int mi = 0; mi < 4; ++mi) {
#pragma unroll
        for (int r = 0; r < 4; ++r) {
          int rowg = rbase + mi * 16 + r;
          int b = rowg >> 11, t = rowg & 2047;
          dst[(size_t)(((b * 16 + h) * 2048 + t) * 64 + hd)] = f2bf(acc[mi][ni][r] * scl);
        }
      }
    }
  } else {
#pragma unroll
    for (int mi = 0; mi < 4; ++mi)
#pragma unroll
      for (int r = 0; r < 4; ++r) {
        int rowg = rbase + mi * 16 + r;
#pragma unroll
        for (int ni = 0; ni < 4; ++ni)
          Cf[(size_t)rowg * 1024 + cbase + ni * 16] = acc[mi][ni][r];
      }
  }
}

// ---------------- causal flash attention (v3, tr-read address fixed) ----------------
// grid (pair=16, bh=32); block does q-tiles {31-p, p} -> 33 k-tiles, balanced.
// Swapped QK^T AND swapped PV: lane owns q = l15 end-to-end; P stays in
// registers; V staged subtiled via global_load_lds, consumed with per-lane
// ds_read_b64_tr_b16.
__global__ __launch_bounds__(256) void k_attn(const u16* __restrict__ Q,
                                              const u16* __restrict__ K,
                                              const u16* __restrict__ V,
                                              u16* __restrict__ Y) {
  __shared__ u16 Kl[2][64 * 64];   // [kk][hd], chunk ^= kk&7
  __shared__ u16 Vtr[2][64 * 64];  // subtiled: ((hd>>4)*16 + (k>>2))*64 + (k&3)*16 + (hd&15)
  const int tid = threadIdx.x, lane = tid & 63, wave = tid >> 6;
  const int l15 = lane & 15, l4 = lane >> 4;
  const int pr = blockIdx.x, bh = blockIdx.y;
  const u16* Qb = Q + (size_t)bh * 2048 * 64;
  const u16* Kb = K + (size_t)bh * 2048 * 64;
  const u16* Vb = V + (size_t)bh * 2048 * 64;
  const int b = bh >> 4, h = bh & 15;
  const f32x4 fz = {0.f, 0.f, 0.f, 0.f};

  // K staging (pre-swizzled global source, linear LDS dest)
  const int kk0 = wave * 16 + (lane >> 3);
  const int kk1 = kk0 + 8;
  const int lcol0 = ((lane & 7) ^ (kk0 & 7)) * 8;
  const int lcol1 = ((lane & 7) ^ (kk1 & 7)) * 8;
  // V staging: linear LDS offset o -> (k, hd) of the subtiled layout
  int vk[2], vhd[2];
#pragma unroll
  for (int i = 0; i < 2; ++i) {
    int o = (wave * 2 + i) * 512 + lane * 8;
    vk[i] = ((o >> 6) & 15) * 4 + ((o >> 4) & 3);
    vhd[i] = ((o >> 10) << 4) + (o & 8);
  }

  auto stage = [&](int buf, int kt) {
    gl_lds16(Kb + (size_t)(kt * 64 + kk0) * 64 + lcol0, &Kl[buf][(wave * 2 + 0) * 512]);
    gl_lds16(Kb + (size_t)(kt * 64 + kk1) * 64 + lcol1, &Kl[buf][(wave * 2 + 1) * 512]);
    gl_lds16(Vb + (size_t)(kt * 64 + vk[0]) * 64 + vhd[0], &Vtr[buf][(wave * 2 + 0) * 512]);
    gl_lds16(Vb + (size_t)(kt * 64 + vk[1]) * 64 + vhd[1], &Vtr[buf][(wave * 2 + 1) * 512]);
  };

#pragma unroll 1
  for (int half = 0; half < 2; ++half) {
    const int qt = half == 0 ? (31 - pr) : pr;
    bf16x8 qf[2];
    {
      int qrow = qt * 64 + wave * 16 + l15;
      qf[0] = *(const bf16x8*)&Qb[(size_t)qrow * 64 + l4 * 8];
      qf[1] = *(const bf16x8*)&Qb[(size_t)qrow * 64 + 32 + l4 * 8];
    }
    f32x4 accO[4] = {fz, fz, fz, fz};  // accO[hb][r] = O^T[hd=hb*16+l4*4+r][q=l15]
    float m = -1e30f, lsum = 0.f;

    stage(0, 0);
    __syncthreads();

    int cur = 0;
#pragma unroll 1
    for (int kt = 0; kt <= qt; ++kt) {
      if (kt < qt) stage(cur ^ 1, kt + 1);

      // S^T = K Q^T : accS[nb] holds S[q=l15][k=nb*16+l4*4+r]
      f32x4 accS[4] = {fz, fz, fz, fz};
      __builtin_amdgcn_s_setprio(1);
#pragma unroll
      for (int s = 0; s < 2; ++s)
#pragma unroll
        for (int nb = 0; nb < 4; ++nb) {
          int kk = nb * 16 + l15;
          int ch = (s * 4 + l4) ^ (kk & 7);
          bf16x8 kf = *(const bf16x8*)&Kl[cur][kk * 64 + ch * 8];
          accS[nb] = __builtin_amdgcn_mfma_f32_16x16x32_bf16(kf, qf[s], accS[nb], 0, 0, 0);
        }
      __builtin_amdgcn_s_setprio(0);

      // causal mask (diagonal tile only)
      float sv[4][4];
      if (kt == qt) {
        int qg = wave * 16 + l15;
#pragma unroll
        for (int nb = 0; nb < 4; ++nb)
#pragma unroll
          for (int r = 0; r < 4; ++r) {
            int kg = nb * 16 + l4 * 4 + r;
            sv[nb][r] = kg > qg ? -1e30f : accS[nb][r];
          }
      } else {
#pragma unroll
        for (int nb = 0; nb < 4; ++nb)
#pragma unroll
          for (int r = 0; r < 4; ++r) sv[nb][r] = accS[nb][r];
      }

      // per-lane online softmax (lane owns q = l15; l4 groups share q via xor 16/32)
      float mx = sv[0][0];
#pragma unroll
      for (int nb = 0; nb < 4; ++nb)
#pragma unroll
        for (int r = 0; r < 4; ++r) mx = fmaxf(mx, sv[nb][r]);
      mx = fmaxf(mx, __shfl_xor(mx, 16));
      mx = fmaxf(mx, __shfl_xor(mx, 32));
      float mnew = fmaxf(m, mx);
      float alpha = __expf(m - mnew);
      m = mnew;
      float p[4][4];
      float rsum = 0.f;
#pragma unroll
      for (int nb = 0; nb < 4; ++nb)
#pragma unroll
        for (int r = 0; r < 4; ++r) {
          p[nb][r] = __expf(sv[nb][r] - mnew);
          rsum += p[nb][r];
        }
      rsum += __shfl_xor(rsum, 16);
      rsum += __shfl_xor(rsum, 32);
      lsum = lsum * alpha + rsum;

      // rescale O^T by own-lane alpha (no shuffles: col q = l15)
#pragma unroll
      for (int hb = 0; hb < 4; ++hb)
#pragma unroll
        for (int r = 0; r < 4; ++r) accO[hb][r] *= alpha;

      // O^T += V^T P^T. A-frag = per-lane tr-read of subtiled V;
      // B-frag = lane's own p values (k-map matches tr-read's k-map:
      // elem j of lane group l4 <-> k = s*32 + (j>>2)*16 + l4*4 + (j&3)).
#pragma unroll
      for (int s = 0; s < 2; ++s) {
        u32x4 w;
        w.x = cvt_pk_bf16(p[2 * s][0], p[2 * s][1]);
        w.y = cvt_pk_bf16(p[2 * s][2], p[2 * s][3]);
        w.z = cvt_pk_bf16(p[2 * s + 1][0], p[2 * s + 1][1]);
        w.w = cvt_pk_bf16(p[2 * s + 1][2], p[2 * s + 1][3]);
        bf16x8 pf = __builtin_bit_cast(bf16x8, w);
        bf16x4 ta[4], tb[4];
#pragma unroll
        for (int hb = 0; hb < 4; ++hb) {
          ta[hb] = tr16(&Vtr[cur][(hb * 16 + s * 8) * 64 + lane * 4]);
          tb[hb] = tr16(&Vtr[cur][(hb * 16 + s * 8 + 4) * 64 + lane * 4]);
        }
        asm volatile("s_waitcnt lgkmcnt(0)" ::: "memory");
        __builtin_amdgcn_sched_barrier(0);
        __builtin_amdgcn_s_setprio(1);
#pragma unroll
        for (int hb = 0; hb < 4; ++hb) {
          bf16x8 vf = __builtin_shufflevector(ta[hb], tb[hb], 0, 1, 2, 3, 4, 5, 6, 7);
          accO[hb] = __builtin_amdgcn_mfma_f32_16x16x32_bf16(vf, pf, accO[hb], 0, 0, 0);
        }
        __builtin_amdgcn_s_setprio(0);
      }
      __syncthreads();
      cur ^= 1;
    }

    // epilogue: per-lane 1/lsum; lane (l15,l4) writes O[q=l15][hb*16+l4*4+0..3]
    {
      float inv = 1.0f / lsum;
      int qg = qt * 64 + wave * 16 + l15;
      u16* yrow = Y + (size_t)(b * 2048 + qg) * 1024 + h * 64;
#pragma unroll
      for (int hb = 0; hb < 4; ++hb) {
        uint2 pk;
        pk.x = cvt_pk_bf16(accO[hb][0] * inv, accO[hb][1] * inv);
        pk.y = cvt_pk_bf16(accO[hb][2] * inv, accO[hb][3] * inv);
        *(uint2*)&yrow[hb * 16 + l4 * 4] = pk;
      }
    }
  }
}

extern "C" void kernel_launch(void* const* d_in, const int* in_sizes, int n_in,
                              void* d_out, int out_size, void* d_ws, size_t ws_size,
                              hipStream_t stream) {
  const float* x = (const float*)d_in[0];       // [2,2048,1024]
  const float* Wqkv = (const float*)d_in[1];    // [1024,3072]
  const float* Wproj = (const float*)d_in[2];   // [1024,1024]
  float* out = (float*)d_out;                   // [2,2048,1024] f32

  char* ws = (char*)d_ws;
  u16* Xb  = (u16*)(ws + 0);                    // 8 MB  [4096][1024]
  u16* Wqt = (u16*)(ws + ((size_t)8 << 20));    // 6 MB  [3072][1024]
  u16* Wpt = (u16*)(ws + ((size_t)14 << 20));   // 2 MB  [1024][1024]
  u16* Qs  = (u16*)(ws + ((size_t)16 << 20));   // 8 MB  [2,16,2048,64]
  u16* Ks  = (u16*)(ws + ((size_t)24 << 20));   // 8 MB
  u16* Vs  = (u16*)(ws + ((size_t)32 << 20));   // 8 MB
  u16* Yb  = (u16*)(ws + ((size_t)40 << 20));   // 8 MB  [4096][1024]

  k_cast<<<2048, 256, 0, stream>>>(x, Xb, 4096 * 1024 / 8);
  k_tcast<<<dim3(96, 32), 256, 0, stream>>>(Wqkv, Wqt, 1024, 3072);
  k_tcast<<<dim3(32, 32), 256, 0, stream>>>(Wproj, Wpt, 1024, 1024);
  k_gemm<0><<<dim3(24, 32), 256, 0, stream>>>(Xb, Wqt, Qs, Ks, Vs, nullptr, 1024);
  k_attn<<<dim3(16, 32), 256, 0, stream>>>(Qs, Ks, Vs, Yb);
  k_gemm<1><<<dim3(8, 32), 256, 0, stream>>>(Yb, Wpt, nullptr, nullptr, nullptr, out, 1024);
}

// Round 5
// 126.127 us; speedup vs baseline: 1.8441x; 1.0216x over previous
//
#include <hip/hip_runtime.h>

typedef __bf16 bf16x8 __attribute__((ext_vector_type(8)));
typedef __bf16 bf16x4 __attribute__((ext_vector_type(4)));
typedef float f32x4 __attribute__((ext_vector_type(4)));
typedef unsigned short u16;
typedef unsigned int u32;
typedef u32 u32x4 __attribute__((ext_vector_type(4)));

// round-to-nearest-even f32 -> bf16
__device__ __forceinline__ u16 f2bf(float f) {
  u32 u = __builtin_bit_cast(u32, f);
  u += 0x7fffu + ((u >> 16) & 1u);
  return (u16)(u >> 16);
}

// packed f32x2 -> bf16x2 (RNE); low u16 = first arg (verified R2/R4)
__device__ __forceinline__ u32 cvt_pk_bf16(float lo, float hi) {
  u32 r;
  asm("v_cvt_pk_bf16_f32 %0, %1, %2" : "=v"(r) : "v"(lo), "v"(hi));
  return r;
}

// raw v_exp_f32: r = 2^x (scores are pre-scaled to log2 domain)
__device__ __forceinline__ float ex2(float x) {
  float r;
  asm("v_exp_f32 %0, %1" : "=v"(r) : "v"(x));
  return r;
}

// async global->LDS, 16B per lane. LDS dest = wave-uniform base + lane*16.
__device__ __forceinline__ void gl_lds16(const u16* g, u16* l) {
  __builtin_amdgcn_global_load_lds(
      (const __attribute__((address_space(1))) u32*)g,
      (__attribute__((address_space(3))) u32*)l, 16, 0, 0);
}

// LDS transpose read. Per-lane address REQUIRED: p = base + lane*4 (elems).
// Lane l receives elems base[(l>>4)*64 + j*16 + (l&15)], j=0..3 (verified R4).
__device__ __forceinline__ bf16x4 tr16(const u16* p) {
  bf16x4 r;
  auto lp = (const __attribute__((address_space(3))) u16*)p;
  asm volatile("ds_read_b64_tr_b16 %0, %1" : "=&v"(r) : "v"(lp));
  return r;
}

// ---------------- cast x: f32 -> bf16, 8 elems/thread ----------------
__global__ __launch_bounds__(256) void k_cast(const float* __restrict__ in,
                                              u16* __restrict__ out, int n8) {
  int i = blockIdx.x * 256 + threadIdx.x;
  if (i >= n8) return;
  const float4* p = (const float4*)in + (size_t)i * 2;
  float4 a = p[0], b = p[1];
  u16 r[8] = {f2bf(a.x), f2bf(a.y), f2bf(a.z), f2bf(a.w),
              f2bf(b.x), f2bf(b.y), f2bf(b.z), f2bf(b.w)};
  ((uint4*)out)[i] = *(const uint4*)r;
}

// ---------- transpose+cast: W [K][N] f32 -> Wt [N][K] bf16 ----------
__global__ __launch_bounds__(256) void k_tcast(const float* __restrict__ in,
                                               u16* __restrict__ out, int K, int N) {
  __shared__ float tile[32][33];
  int n0 = blockIdx.x * 32, k0 = blockIdx.y * 32;
  int c = threadIdx.x & 31, r0 = (threadIdx.x >> 5) * 4;
#pragma unroll
  for (int rr = 0; rr < 4; ++rr) {
    int r = r0 + rr;
    tile[r][c] = in[(size_t)(k0 + r) * N + n0 + c];
  }
  __syncthreads();
#pragma unroll
  for (int rr = 0; rr < 4; ++rr) {
    int r = r0 + rr;
    out[(size_t)(n0 + r) * K + k0 + c] = f2bf(tile[c][r]);
  }
}

// ---------------- bf16 GEMM: C[M,N] = A[M,K] * Bt[N,K]^T ----------------
// 128x128 tile, 4 waves (2x2), BK=32. LDS chunk-swizzle: pchunk = chunk ^ ((row>>1)&3).
// EPI 0: Q scaled by 0.125*log2(e) (attention works in exp2 domain).
template <int EPI>
__global__ __launch_bounds__(256) void k_gemm(const u16* __restrict__ A,
                                              const u16* __restrict__ Bt,
                                              u16* __restrict__ Qp, u16* __restrict__ Kp,
                                              u16* __restrict__ Vp, float* __restrict__ Cf,
                                              int K) {
  __shared__ u16 As[128 * 32];
  __shared__ u16 Bs[128 * 32];
  const int tid = threadIdx.x;
  const int lane = tid & 63, wave = tid >> 6;
  const int l15 = lane & 15, l4 = lane >> 4;
  const int wr = wave >> 1, wc = wave & 1;
  const int tm = blockIdx.y, tn = blockIdx.x;

  int srow[2], scol[2];
#pragma unroll
  for (int i = 0; i < 2; ++i) {
    int row = (wave * 2 + i) * 16 + (lane >> 2);
    srow[i] = row;
    scol[i] = ((lane & 3) ^ ((row >> 1) & 3)) * 8;
  }

  const f32x4 fz = {0.f, 0.f, 0.f, 0.f};
  f32x4 acc[4][4];
#pragma unroll
  for (int a = 0; a < 4; ++a)
#pragma unroll
    for (int b = 0; b < 4; ++b) acc[a][b] = fz;

  const int nk = K >> 5;
  for (int kt = 0; kt < nk; ++kt) {
#pragma unroll
    for (int i = 0; i < 2; ++i) {
      gl_lds16(A + (size_t)(tm * 128 + srow[i]) * K + kt * 32 + scol[i],
               &As[(wave * 2 + i) * 512]);
      gl_lds16(Bt + (size_t)(tn * 128 + srow[i]) * K + kt * 32 + scol[i],
               &Bs[(wave * 2 + i) * 512]);
    }
    __syncthreads();
    bf16x8 af[4], bfr[4];
#pragma unroll
    for (int mi = 0; mi < 4; ++mi) {
      int row = wr * 64 + mi * 16 + l15;
      int pch = l4 ^ ((row >> 1) & 3);
      af[mi] = *(const bf16x8*)&As[row * 32 + pch * 8];
    }
#pragma unroll
    for (int ni = 0; ni < 4; ++ni) {
      int row = wc * 64 + ni * 16 + l15;
      int pch = l4 ^ ((row >> 1) & 3);
      bfr[ni] = *(const bf16x8*)&Bs[row * 32 + pch * 8];
    }
#pragma unroll
    for (int mi = 0; mi < 4; ++mi)
#pragma unroll
      for (int ni = 0; ni < 4; ++ni)
        acc[mi][ni] = __builtin_amdgcn_mfma_f32_16x16x32_bf16(af[mi], bfr[ni],
                                                              acc[mi][ni], 0, 0, 0);
    __syncthreads();
  }

  const int rbase = tm * 128 + wr * 64 + l4 * 4;
  const int cbase = tn * 128 + wc * 64 + l15;
  if (EPI == 0) {
#pragma unroll
    for (int ni = 0; ni < 4; ++ni) {
      int col = cbase + ni * 16;
      int which = col >> 10;
      int d = col & 1023;
      int h = d >> 6, hd = d & 63;
      u16* dst = which == 0 ? Qp : (which == 1 ? Kp : Vp);
      float scl = which == 0 ? 0.180336880f : 1.0f;  // 0.125 * log2(e)
#pragma unroll
      for (int mi = 0; mi < 4; ++mi) {
#pragma unroll
        for (int r = 0; r < 4; ++r) {
          int rowg = rbase + mi * 16 + r;
          int b = rowg >> 11, t = rowg & 2047;
          dst[(size_t)(((b * 16 + h) * 2048 + t) * 64 + hd)] = f2bf(acc[mi][ni][r] * scl);
        }
      }
    }
  } else {
#pragma unroll
    for (int mi = 0; mi < 4; ++mi)
#pragma unroll
      for (int r = 0; r < 4; ++r) {
        int rowg = rbase + mi * 16 + r;
#pragma unroll
        for (int ni = 0; ni < 4; ++ni)
          Cf[(size_t)rowg * 1024 + cbase + ni * 16] = acc[mi][ni][r];
      }
  }
}

// ---------------- causal flash attention (v4) ----------------
// grid (pair=16, bh=32). Block processes q-tiles qtA=31-p' and qtB=p'
// CONCURRENTLY in one k-loop (shared K/V staging, 2x ILP per wave).
// Swapped QK^T + swapped PV; defer-max softmax (T13, THR=8 in log2 domain);
// scores pre-scaled to exp2 domain at GEMM1.
__global__ __launch_bounds__(256) void k_attn(const u16* __restrict__ Q,
                                              const u16* __restrict__ K,
                                              const u16* __restrict__ V,
                                              u16* __restrict__ Y) {
  __shared__ u16 Kl[2][64 * 64];   // [kk][hd], chunk ^= kk&7
  __shared__ u16 Vtr[2][64 * 64];  // subtiled: ((hd>>4)*16+(k>>2))*64 + (k&3)*16 + (hd&15)
  const int tid = threadIdx.x, lane = tid & 63, wave = tid >> 6;
  const int l15 = lane & 15, l4 = lane >> 4;
  const int bh = blockIdx.y;
  const int pp = (blockIdx.x + ((blockIdx.y >> 4) << 3)) & 15;  // co-res blocks differ
  const int qtA = 31 - pp, qtB = pp;
  const u16* Qb = Q + (size_t)bh * 2048 * 64;
  const u16* Kb = K + (size_t)bh * 2048 * 64;
  const u16* Vb = V + (size_t)bh * 2048 * 64;
  const int b = bh >> 4, h = bh & 15;
  const f32x4 fz = {0.f, 0.f, 0.f, 0.f};

  // K staging (pre-swizzled global source, linear LDS dest)
  const int kk0 = wave * 16 + (lane >> 3);
  const int kk1 = kk0 + 8;
  const int lcol0 = ((lane & 7) ^ (kk0 & 7)) * 8;
  const int lcol1 = ((lane & 7) ^ (kk1 & 7)) * 8;
  // V staging: linear LDS offset o -> (k, hd) of the subtiled layout
  int vk[2], vhd[2];
#pragma unroll
  for (int i = 0; i < 2; ++i) {
    int o = (wave * 2 + i) * 512 + lane * 8;
    vk[i] = ((o >> 6) & 15) * 4 + ((o >> 4) & 3);
    vhd[i] = ((o >> 10) << 4) + (o & 8);
  }

  auto stage = [&](int buf, int kt) {
    gl_lds16(Kb + (size_t)(kt * 64 + kk0) * 64 + lcol0, &Kl[buf][(wave * 2 + 0) * 512]);
    gl_lds16(Kb + (size_t)(kt * 64 + kk1) * 64 + lcol1, &Kl[buf][(wave * 2 + 1) * 512]);
    gl_lds16(Vb + (size_t)(kt * 64 + vk[0]) * 64 + vhd[0], &Vtr[buf][(wave * 2 + 0) * 512]);
    gl_lds16(Vb + (size_t)(kt * 64 + vk[1]) * 64 + vhd[1], &Vtr[buf][(wave * 2 + 1) * 512]);
  };

  // per-tile compute pieces (all array indices compile-time constant)
  auto qk = [&](const bf16x8* qf, f32x4* accS, int cur) {
    __builtin_amdgcn_s_setprio(1);
#pragma unroll
    for (int s = 0; s < 2; ++s)
#pragma unroll
      for (int nb = 0; nb < 4; ++nb) {
        int kk = nb * 16 + l15;
        int ch = (s * 4 + l4) ^ (kk & 7);
        bf16x8 kf = *(const bf16x8*)&Kl[cur][kk * 64 + ch * 8];
        accS[nb] = __builtin_amdgcn_mfma_f32_16x16x32_bf16(kf, qf[s], accS[nb], 0, 0, 0);
      }
    __builtin_amdgcn_s_setprio(0);
  };

  auto smx = [&](const f32x4* accS, float (*p)[4], float& m, float& lsum,
                 f32x4* accO, bool diag) {
    float sv[4][4];
    if (diag) {
      int qg = wave * 16 + l15;
#pragma unroll
      for (int nb = 0; nb < 4; ++nb)
#pragma unroll
        for (int r = 0; r < 4; ++r) {
          int kg = nb * 16 + l4 * 4 + r;
          sv[nb][r] = kg > qg ? -1e30f : accS[nb][r];
        }
    } else {
#pragma unroll
      for (int nb = 0; nb < 4; ++nb)
#pragma unroll
        for (int r = 0; r < 4; ++r) sv[nb][r] = accS[nb][r];
    }
    float mx = sv[0][0];
#pragma unroll
    for (int nb = 0; nb < 4; ++nb)
#pragma unroll
      for (int r = 0; r < 4; ++r) mx = fmaxf(mx, sv[nb][r]);
    // defer-max: common path has NO cross-lane ops and NO rescale
    if (!__all(mx <= m + 8.0f)) {
      float mr = fmaxf(mx, __shfl_xor(mx, 16));
      mr = fmaxf(mr, __shfl_xor(mr, 32));
      float mnew = fmaxf(m, mr);
      float alpha = ex2(m - mnew);
      m = mnew;
      lsum *= alpha;
#pragma unroll
      for (int hb = 0; hb < 4; ++hb)
#pragma unroll
        for (int r = 0; r < 4; ++r) accO[hb][r] *= alpha;
    }
    float rsum = 0.f;
#pragma unroll
    for (int nb = 0; nb < 4; ++nb)
#pragma unroll
      for (int r = 0; r < 4; ++r) {
        p[nb][r] = ex2(sv[nb][r] - m);
        rsum += p[nb][r];
      }
    lsum += rsum;  // group-partial; merged at epilogue
  };

  auto pv = [&](const float (*p)[4], f32x4* accO, int cur) {
#pragma unroll
    for (int s = 0; s < 2; ++s) {
      u32x4 w;
      w.x = cvt_pk_bf16(p[2 * s][0], p[2 * s][1]);
      w.y = cvt_pk_bf16(p[2 * s][2], p[2 * s][3]);
      w.z = cvt_pk_bf16(p[2 * s + 1][0], p[2 * s + 1][1]);
      w.w = cvt_pk_bf16(p[2 * s + 1][2], p[2 * s + 1][3]);
      bf16x8 pf = __builtin_bit_cast(bf16x8, w);
      bf16x4 ta[4], tb[4];
#pragma unroll
      for (int hb = 0; hb < 4; ++hb) {
        ta[hb] = tr16(&Vtr[cur][(hb * 16 + s * 8) * 64 + lane * 4]);
        tb[hb] = tr16(&Vtr[cur][(hb * 16 + s * 8 + 4) * 64 + lane * 4]);
      }
      asm volatile("s_waitcnt lgkmcnt(0)" ::: "memory");
      __builtin_amdgcn_sched_barrier(0);
      __builtin_amdgcn_s_setprio(1);
#pragma unroll
      for (int hb = 0; hb < 4; ++hb) {
        bf16x8 vf = __builtin_shufflevector(ta[hb], tb[hb], 0, 1, 2, 3, 4, 5, 6, 7);
        accO[hb] = __builtin_amdgcn_mfma_f32_16x16x32_bf16(vf, pf, accO[hb], 0, 0, 0);
      }
      __builtin_amdgcn_s_setprio(0);
    }
  };

  // load Q fragments for both tiles
  bf16x8 qfA[2], qfB[2];
  {
    int qrA = qtA * 64 + wave * 16 + l15;
    int qrB = qtB * 64 + wave * 16 + l15;
    qfA[0] = *(const bf16x8*)&Qb[(size_t)qrA * 64 + l4 * 8];
    qfA[1] = *(const bf16x8*)&Qb[(size_t)qrA * 64 + 32 + l4 * 8];
    qfB[0] = *(const bf16x8*)&Qb[(size_t)qrB * 64 + l4 * 8];
    qfB[1] = *(const bf16x8*)&Qb[(size_t)qrB * 64 + 32 + l4 * 8];
  }
  f32x4 oA[4] = {fz, fz, fz, fz}, oB[4] = {fz, fz, fz, fz};
  float mA = -1e30f, lsA = 0.f, mB = -1e30f, lsB = 0.f;

  stage(0, 0);
  __syncthreads();

  int cur = 0;
#pragma unroll 1
  for (int kt = 0; kt <= qtA; ++kt) {
    if (kt < qtA) stage(cur ^ 1, kt + 1);
    const bool actB = kt <= qtB;
    f32x4 sA[4] = {fz, fz, fz, fz};
    f32x4 sB[4] = {fz, fz, fz, fz};
    qk(qfA, sA, cur);
    if (actB) qk(qfB, sB, cur);
    float pA[4][4], pB[4][4];
    smx(sA, pA, mA, lsA, oA, kt == qtA);
    if (actB) smx(sB, pB, mB, lsB, oB, kt == qtB);
    pv(pA, oA, cur);
    if (actB) pv(pB, oB, cur);
    __syncthreads();
    cur ^= 1;
  }

  // epilogue: merge group-partial lsum (2 shuffles), divide, store
  auto epi = [&](f32x4* accO, float lsum, int qt) {
    float t = lsum + __shfl_xor(lsum, 16);
    t += __shfl_xor(t, 32);
    float inv = 1.0f / t;
    int qg = qt * 64 + wave * 16 + l15;
    u16* yrow = Y + (size_t)(b * 2048 + qg) * 1024 + h * 64;
#pragma unroll
    for (int hb = 0; hb < 4; ++hb) {
      uint2 pk;
      pk.x = cvt_pk_bf16(accO[hb][0] * inv, accO[hb][1] * inv);
      pk.y = cvt_pk_bf16(accO[hb][2] * inv, accO[hb][3] * inv);
      *(uint2*)&yrow[hb * 16 + l4 * 4] = pk;
    }
  };
  epi(oA, lsA, qtA);
  epi(oB, lsB, qtB);
}

extern "C" void kernel_launch(void* const* d_in, const int* in_sizes, int n_in,
                              void* d_out, int out_size, void* d_ws, size_t ws_size,
                              hipStream_t stream) {
  const float* x = (const float*)d_in[0];       // [2,2048,1024]
  const float* Wqkv = (const float*)d_in[1];    // [1024,3072]
  const float* Wproj = (const float*)d_in[2];   // [1024,1024]
  float* out = (float*)d_out;                   // [2,2048,1024] f32

  char* ws = (char*)d_ws;
  u16* Xb  = (u16*)(ws + 0);                    // 8 MB  [4096][1024]
  u16* Wqt = (u16*)(ws + ((size_t)8 << 20));    // 6 MB  [3072][1024]
  u16* Wpt = (u16*)(ws + ((size_t)14 << 20));   // 2 MB  [1024][1024]
  u16* Qs  = (u16*)(ws + ((size_t)16 << 20));   // 8 MB  [2,16,2048,64]
  u16* Ks  = (u16*)(ws + ((size_t)24 << 20));   // 8 MB
  u16* Vs  = (u16*)(ws + ((size_t)32 << 20));   // 8 MB
  u16* Yb  = (u16*)(ws + ((size_t)40 << 20));   // 8 MB  [4096][1024]

  k_cast<<<2048, 256, 0, stream>>>(x, Xb, 4096 * 1024 / 8);
  k_tcast<<<dim3(96, 32), 256, 0, stream>>>(Wqkv, Wqt, 1024, 3072);
  k_tcast<<<dim3(32, 32), 256, 0, stream>>>(Wproj, Wpt, 1024, 1024);
  k_gemm<0><<<dim3(24, 32), 256, 0, stream>>>(Xb, Wqt, Qs, Ks, Vs, nullptr, 1024);
  k_attn<<<dim3(16, 32), 256, 0, stream>>>(Qs, Ks, Vs, Yb);
  k_gemm<1><<<dim3(8, 32), 256, 0, stream>>>(Yb, Wpt, nullptr, nullptr, nullptr, out, 1024);
}